// Round 7
// baseline (124.759 us; speedup 1.0000x reference)
//
#include <hip/hip_runtime.h>

// Xonv2D: per-location conv. B=32, CIN=16, H=W=64, COUT=32, K=3, pad=1.
// out[b,o,h,w] = sum_{c,kh,kw} x[b,c,h+kh-1,w+kw-1] * W[h,w,o,c,kh,kw] + bias[h,w,o]
//
// R7 = R6 + FIXED XCD swizzle. R4/R6 used XCD = h%8 -> adjacent h-rows on
// different XCDs -> the 3x h-halo of x staging never reuses L2 (~63 MB of x
// HBM traffic; 156 MB total at 4.4 TB/s = the whole 34.6us kernel time).
// Now XCD = bi&7 owns the h-band [8*xcd, 8*xcd+8) x all 4 w-groups: the
// band's x working set is 10 rows x 16 c x 32 b x 256 B = 1.31 MB < 4 MB L2,
// staged concurrently by the XCD's 32 blocks -> halo + column overlap served
// from L2. Everything else identical to R6 (depth-4 weight prefetch, 16-wave
// blocks, full-line stores, compile-time gather tables).

#define CIN  16
#define HW_  4096            // H*W
#define PP   144             // CIN*3*3
#define RST  20              // hw per (b, c*3+r) row: slot = col - w0 + 2
#define BST  962             // hw per b: 48*20 + 2 pad (dw stride 481 == 1 mod 32)

typedef float v4f  __attribute__((ext_vector_type(4)));
typedef float v16f __attribute__((ext_vector_type(16)));
typedef short v8s  __attribute__((ext_vector_type(8)));

__device__ __forceinline__ unsigned short f2bf(float f) {
    unsigned int u = __builtin_bit_cast(unsigned int, f);
    u += 0x7fffu + ((u >> 16) & 1u);          // RNE
    return (unsigned short)(u >> 16);
}
__device__ __forceinline__ unsigned int pk2(float a, float b) {
    return (unsigned int)f2bf(a) | ((unsigned int)f2bf(b) << 16);
}
__device__ __forceinline__ constexpr int offp(int p) {
    // p = c*9 + r*3 + kw  ->  LDS hw offset (row part + kw + 1)
    const int c = p / 9, rem = p % 9, r = rem / 3, kw = rem % 3;
    return (c * 3 + r) * RST + kw + 1;
}

__global__ __launch_bounds__(1024, 4) void xonv_kernel(
    const float* __restrict__ x,
    const float* __restrict__ wt,
    const float* __restrict__ bias,
    float* __restrict__ out)
{
    const int t  = threadIdx.x;
    const int bi = blockIdx.x;                 // 0..255
    // Band swizzle: XCD (= bi%8) owns h in [8*xcd, 8*xcd+8), all 4 w-groups.
    const int xcd = bi & 7;
    const int idx = bi >> 3;                   // 0..31
    const int h   = xcd * 8 + (idx & 7);
    const int wg  = idx >> 3;                  // 0..3
    const int w0  = wg << 4;

    __shared__ unsigned short xs[32 * BST];    // 61,568 B
    float* ol = (float*)xs;                    // epilogue alias (34,816 B)

    const int l  = t & 63;
    const int wv = t >> 6;                     // wave = location 0..15
    const int w  = w0 + wv;
    const int o  = l & 31;                     // out-channel col / batch lane idx
    const int kh = l >> 5;                     // k-half (0/1)

    // ---- weight slice pointers; depth-4 rotating prefetch issued EARLY ----
    const float* wp = wt + (size_t)(h * 64 + w) * (32 * PP)
                         + (size_t)o * PP + kh * 8;
    float4 ca[4], cb[4];
#pragma unroll
    for (int s = 0; s < 4; ++s) {
        ca[s] = *(const float4*)(wp + s * 16);
        cb[s] = *(const float4*)(wp + s * 16 + 4);
    }
    const float bia = bias[(size_t)(h * 64 + w) * 32 + o];

    // ---------------- stage x windows: 1536 rows x 6 float4 ----------------
    // job j: rid = j/6 (row = b*48 + c*3 + r), sub = j%6; window col w0-4+sub*4
    const int wstart = w0 - 4;
#pragma unroll
    for (int i = 0; i < 9; ++i) {
        const int j   = t + i * 1024;
        const int rid = (int)(((unsigned)j * 43691u) >> 18);   // j/6
        const int sub = j - rid * 6;
        const int b   = (rid * 683) >> 15;                     // rid/48
        const int cr  = rid - b * 48;
        const int c   = (cr * 43) >> 7;                        // cr/3
        const int r   = cr - c * 3;
        const int row = h + r - 1;
        const int col4 = wstart + sub * 4;
        float4 f = {0.f, 0.f, 0.f, 0.f};
        if ((unsigned)row < 64u && (unsigned)col4 <= 60u)
            f = *(const float4*)(x + ((size_t)(b * CIN + c)) * HW_
                                   + row * 64 + col4);
        unsigned short* dst = xs + b * BST + cr * RST;
        if (sub == 0) {
            ((unsigned int*)dst)[0] = pk2(f.z, f.w);           // slots 0,1
        } else if (sub == 5) {
            ((unsigned int*)dst)[9] = pk2(f.x, f.y);           // slots 18,19
        } else {
            unsigned int* d = (unsigned int*)(dst + sub * 4 - 2);
            d[0] = pk2(f.x, f.y);                              // slots 4s-2..
            d[1] = pk2(f.z, f.w);
        }
    }
    __syncthreads();

    // ---------------- compute: one wave per location, 9 x 32x32x16 ---------
    const int gb = o * BST + wv;               // per-lane gather base (hw)

    v16f acc;
#pragma unroll
    for (int i = 0; i < 16; ++i) acc[i] = 0.f;

#pragma unroll
    for (int kc = 0; kc < 9; ++kc) {
        const int slot = kc & 3;

        // pack B-frag from the slice loaded 4 iterations ago
        union { unsigned int u[4]; v8s s; } ub;
        ub.u[0] = pk2(ca[slot].x, ca[slot].y);
        ub.u[1] = pk2(ca[slot].z, ca[slot].w);
        ub.u[2] = pk2(cb[slot].x, cb[slot].y);
        ub.u[3] = pk2(cb[slot].z, cb[slot].w);

        // refill the slot with slice kc+4 (keeps 4 slices in flight)
        if (kc + 4 < 9) {
            ca[slot] = *(const float4*)(wp + (kc + 4) * 16);
            cb[slot] = *(const float4*)(wp + (kc + 4) * 16 + 4);
        }

        v8s a;
#pragma unroll
        for (int j = 0; j < 8; ++j) {
            const int C0 = offp(kc * 16 + j);        // compile-time
            const int C1 = offp(kc * 16 + 8 + j);    // compile-time
            a[j] = (short)xs[gb + (kh ? C1 : C0)];
        }

        acc = __builtin_amdgcn_mfma_f32_32x32x16_bf16(a, ub.s, acc, 0, 0, 0);
    }

    __syncthreads();   // all xs gathers done; reuse LDS as ol[512][17]

    // ---------------- epilogue: two b-halves, full-line stores -------------
#pragma unroll
    for (int half = 0; half < 2; ++half) {
#pragma unroll
        for (int rr = 0; rr < 8; ++rr) {
            const int r     = half * 8 + rr;
            const int browl = (r & 3) + 8 * ((r >> 2) & 1) + 4 * kh;  // 0..15
            ol[(browl * 32 + o) * 17 + wv] = acc[r] + bia;
        }
        __syncthreads();
#pragma unroll
        for (int i2 = 0; i2 < 2; ++i2) {
            const int flat = t + i2 * 1024;
            const int bol  = flat >> 2;            // 0..511 : browl*32+o
            const int q4   = flat & 3;
            const int base = bol * 17 + q4 * 4;
            float4 v;
            v.x = ol[base + 0]; v.y = ol[base + 1];
            v.z = ol[base + 2]; v.w = ol[base + 3];
            const int bg = half * 16 + (bol >> 5);         // batch
            const int og = bol & 31;                       // out-channel
            *(float4*)(out + ((size_t)(bg * 32 + og)) * HW_
                           + h * 64 + w0 + q4 * 4) = v;
        }
        __syncthreads();
    }
}

extern "C" void kernel_launch(void* const* d_in, const int* in_sizes, int n_in,
                              void* d_out, int out_size, void* d_ws, size_t ws_size,
                              hipStream_t stream) {
    const float* x       = (const float*)d_in[0];
    const float* weights = (const float*)d_in[1];
    const float* bias    = (const float*)d_in[2];
    float* out           = (float*)d_out;
    (void)in_sizes; (void)n_in; (void)out_size; (void)d_ws; (void)ws_size;

    dim3 grid(256);     // 8 XCD-bands x 8 h x 4 w-groups
    dim3 block(1024);   // 16 waves = 16 w-locations
    hipLaunchKernelGGL(xonv_kernel, grid, block, 0, stream, x, weights, bias, out);
}